// Round 5
// baseline (1342.669 us; speedup 1.0000x reference)
//
#include <hip/hip_runtime.h>
#include <hip/hip_bf16.h>
#include <stdint.h>

#define BB 64
#define DD 2048
#define VV 50257

struct U2 { unsigned x, y; };

__device__ __forceinline__ unsigned rotl32(unsigned v, int r) {
  return (v << r) | (v >> (32 - r));
}

// JAX threefry2x32 (jax/_src/prng.py lowering), 20 rounds.
__device__ __forceinline__ U2 threefry2x32(unsigned k0, unsigned k1,
                                           unsigned x0, unsigned x1) {
  unsigned k2 = k0 ^ k1 ^ 0x1BD11BDAu;
  x0 += k0; x1 += k1;
#define TF_R4(r1, r2, r3, r4)                         \
  x0 += x1; x1 = rotl32(x1, r1); x1 ^= x0;            \
  x0 += x1; x1 = rotl32(x1, r2); x1 ^= x0;            \
  x0 += x1; x1 = rotl32(x1, r3); x1 ^= x0;            \
  x0 += x1; x1 = rotl32(x1, r4); x1 ^= x0;
  TF_R4(13, 15, 26, 6)   x0 += k1; x1 += k2 + 1u;
  TF_R4(17, 29, 16, 24)  x0 += k2; x1 += k0 + 2u;
  TF_R4(13, 15, 26, 6)   x0 += k0; x1 += k1 + 3u;
  TF_R4(17, 29, 16, 24)  x0 += k1; x1 += k2 + 4u;
  TF_R4(13, 15, 26, 6)   x0 += k2; x1 += k0 + 5u;
#undef TF_R4
  U2 r; r.x = x0; r.y = x1; return r;
}

// Partitionable threefry random_bits, bit_width=32:
// counter u64 e -> words (hi=0, lo=e); 32-bit draw XOR-folds the two
// cipher output words: convert(bits1 ^ bits2, uint32).
__device__ __forceinline__ unsigned jax_random_bits(unsigned e) {
  U2 r = threefry2x32(0u, 42u, 0u, e);
  return r.x ^ r.y;
}

// xT[d][b] = x[b][d] so the GEMM inner loop reads wave-uniform x (scalarizable).
__global__ __launch_bounds__(256) void transpose_kernel(
    const float* __restrict__ x, float* __restrict__ xT) {
  int i = blockIdx.x * 256 + threadIdx.x;
  if (i < BB * DD) {
    int b = i >> 11;      // / 2048
    int d = i & 2047;     // % 2048
    xT[d * BB + b] = x[i];
  }
}

// logits[b][v] = sum_d x[b][d] * W[d][v] + bias[v]
// One output column per thread, 64 accumulators (all B rows). W read once.
__global__ __launch_bounds__(256) void gemm_kernel(
    const float* __restrict__ xT, const float* __restrict__ W,
    const float* __restrict__ bias, float* __restrict__ logits) {
  const int v = blockIdx.x * 256 + threadIdx.x;
  const int vc = (v < VV) ? v : (VV - 1);
  float acc[BB];
#pragma unroll
  for (int b = 0; b < BB; ++b) acc[b] = 0.0f;
  const float* wp = W + vc;
#pragma unroll 2
  for (int d = 0; d < DD; ++d) {
    const float w = wp[(size_t)d * VV];
    const float* xr = xT + d * BB;   // wave-uniform address -> scalar loads
#pragma unroll
    for (int b = 0; b < BB; ++b) acc[b] = fmaf(xr[b], w, acc[b]);
  }
  if (v < VV) {
    const float bv = bias[v];
#pragma unroll
    for (int b = 0; b < BB; ++b) logits[(size_t)b * VV + v] = acc[b] + bv;
  }
}

// Per row (one block): max -> Z=sum(exp) -> binary-search nucleus key threshold
// -> gumbel argmax over kept tokens. All reductions fixed-order (deterministic).
__global__ __launch_bounds__(1024) void nucleus_sample_kernel(
    const float* __restrict__ logits, int* __restrict__ out) {
  __shared__ double sd[1024];
  __shared__ float sf[1024];
  __shared__ int si[1024];
  __shared__ unsigned sdec;
  const int row = blockIdx.x;
  const int tid = threadIdx.x;
  const float* z = logits + (size_t)row * VV;

  // 1) row max (exact)
  float mx = -3.4e38f;
  for (int i = tid; i < VV; i += 1024) mx = fmaxf(mx, z[i]);
  sf[tid] = mx; __syncthreads();
  for (int s = 512; s > 0; s >>= 1) {
    if (tid < s) sf[tid] = fmaxf(sf[tid], sf[tid + s]);
    __syncthreads();
  }
  const float m = sf[0];
  __syncthreads();

  // 2) Z = sum exp(z - m), f64 deterministic tree
  double ss = 0.0;
  for (int i = tid; i < VV; i += 1024) ss += (double)expf(z[i] - m);
  sd[tid] = ss; __syncthreads();
  for (int s = 512; s > 0; s >>= 1) {
    if (tid < s) sd[tid] += sd[tid + s];
    __syncthreads();
  }
  const double C = (double)0.9f * sd[0];   // 0.9f as f32, matching jnp compare
  __syncthreads();

  // 3) binary search: t* = max t with S(t) = sum_{key>=t} exp(z-m) > C.
  //    Keep token iff key(z) >= t*  (== exclusive descending cumsum <= 0.9).
  unsigned lo = 0u, hi = 0xFFFFFFFFu;
  for (int it = 0; it < 32; ++it) {
    if (hi - lo <= 1u) break;
    unsigned mid = lo + ((hi - lo) >> 1);
    double s = 0.0;
    for (int i = tid; i < VV; i += 1024) {
      float zi = z[i];
      unsigned bb = __float_as_uint(zi);
      unsigned key = bb ^ ((bb >> 31) ? 0xFFFFFFFFu : 0x80000000u);
      if (key >= mid) s += (double)expf(zi - m);
    }
    sd[tid] = s; __syncthreads();
    for (int st = 512; st > 0; st >>= 1) {
      if (tid < st) sd[tid] += sd[tid + st];
      __syncthreads();
    }
    if (tid == 0) sdec = (sd[0] > C) ? 1u : 0u;
    __syncthreads();
    if (sdec) lo = mid; else hi = mid;
    __syncthreads();
  }
  const unsigned tstar = lo;

  // 4) gumbel argmax over kept tokens; ties -> lowest index (jnp.argmax).
  float best = -3.4e38f; int bidx = 0x7FFFFFFF;
  for (int i = tid; i < VV; i += 1024) {
    float zi = z[i];
    unsigned bb = __float_as_uint(zi);
    unsigned key = bb ^ ((bb >> 31) ? 0xFFFFFFFFu : 0x80000000u);
    if (key < tstar) continue;
    unsigned e = (unsigned)row * (unsigned)VV + (unsigned)i;  // flat index
    unsigned bits = jax_random_bits(e);
    float f = __uint_as_float((bits >> 9) | 0x3F800000u) - 1.0f;
    float u = fmaxf(1.17549435082228750797e-38f, f);  // minval = tiny
    float g = -logf(-logf(u));
    float sc = zi + g;   // per-row const shift vs log(p)+g -> same argmax
    if (sc > best) { best = sc; bidx = i; }
  }
  sf[tid] = best; si[tid] = bidx; __syncthreads();
  for (int s = 512; s > 0; s >>= 1) {
    if (tid < s) {
      float ob = sf[tid + s]; int oi = si[tid + s];
      if (ob > sf[tid] || (ob == sf[tid] && oi < si[tid])) {
        sf[tid] = ob; si[tid] = oi;
      }
    }
    __syncthreads();
  }
  if (tid == 0) out[row] = si[0];
}

extern "C" void kernel_launch(void* const* d_in, const int* in_sizes, int n_in,
                              void* d_out, int out_size, void* d_ws, size_t ws_size,
                              hipStream_t stream) {
  const float* x = (const float*)d_in[0];
  const float* W = (const float*)d_in[1];
  const float* bias = (const float*)d_in[2];
  int* out = (int*)d_out;
  char* ws = (char*)d_ws;

  float* xT = (float*)ws;                       // 2048*64*4   = 524288 B
  float* logits = (float*)(ws + 524288);        // 64*50257*4  = 12865792 B

  transpose_kernel<<<(BB * DD + 255) / 256, 256, 0, stream>>>(x, xT);
  gemm_kernel<<<(VV + 255) / 256, 256, 0, stream>>>(xT, W, bias, logits);
  nucleus_sample_kernel<<<BB, 1024, 0, stream>>>(logits, out);
}

// Round 6
// 313.363 us; speedup vs baseline: 4.2847x; 4.2847x over previous
//
#include <hip/hip_runtime.h>
#include <hip/hip_bf16.h>
#include <stdint.h>

#define BB 64
#define DD 2048
#define VV 50257
#define NB 4096      // histogram bins
#define MAXC 2048    // boundary-bin collect capacity

struct U2 { unsigned x, y; };

__device__ __forceinline__ unsigned rotl32(unsigned v, int r) {
  return (v << r) | (v >> (32 - r));
}

// JAX threefry2x32 (jax/_src/prng.py lowering), 20 rounds.
__device__ __forceinline__ U2 threefry2x32(unsigned k0, unsigned k1,
                                           unsigned x0, unsigned x1) {
  unsigned k2 = k0 ^ k1 ^ 0x1BD11BDAu;
  x0 += k0; x1 += k1;
#define TF_R4(r1, r2, r3, r4)                         \
  x0 += x1; x1 = rotl32(x1, r1); x1 ^= x0;            \
  x0 += x1; x1 = rotl32(x1, r2); x1 ^= x0;            \
  x0 += x1; x1 = rotl32(x1, r3); x1 ^= x0;            \
  x0 += x1; x1 = rotl32(x1, r4); x1 ^= x0;
  TF_R4(13, 15, 26, 6)   x0 += k1; x1 += k2 + 1u;
  TF_R4(17, 29, 16, 24)  x0 += k2; x1 += k0 + 2u;
  TF_R4(13, 15, 26, 6)   x0 += k0; x1 += k1 + 3u;
  TF_R4(17, 29, 16, 24)  x0 += k1; x1 += k2 + 4u;
  TF_R4(13, 15, 26, 6)   x0 += k2; x1 += k0 + 5u;
#undef TF_R4
  U2 r; r.x = x0; r.y = x1; return r;
}

// VALIDATED (R5): partitionable threefry bits = XOR-fold of both cipher words,
// counter (hi=0, lo=e), key (0, 42).
__device__ __forceinline__ unsigned jax_random_bits(unsigned e) {
  U2 r = threefry2x32(0u, 42u, 0u, e);
  return r.x ^ r.y;
}

__device__ __forceinline__ unsigned mono_key(float zi) {
  unsigned bb = __float_as_uint(zi);
  return bb ^ ((bb >> 31) ? 0xFFFFFFFFu : 0x80000000u);
}

// xT[d][b] = x[b][d] so GEMM inner loop reads wave-uniform x (scalar loads).
__global__ __launch_bounds__(256) void transpose_kernel(
    const float* __restrict__ x, float* __restrict__ xT) {
  int i = blockIdx.x * 256 + threadIdx.x;
  if (i < BB * DD) {
    int b = i >> 11;
    int d = i & 2047;
    xT[d * BB + b] = x[i];
  }
}

// Split-K GEMM: block (bx, s) computes columns [bx*256, +256) for K-slice s.
// (256,1) launch bounds: let acc[64] live in VGPRs (R5 showed VGPR=36 => acc
// was demoted; occupancy now comes from the 8x bigger grid instead).
__global__ __launch_bounds__(256, 1) void gemm_splitk_kernel(
    const float* __restrict__ xT, const float* __restrict__ W,
    float* __restrict__ partial, int kc) {
  const int v = blockIdx.x * 256 + threadIdx.x;
  const int vc = (v < VV) ? v : (VV - 1);
  const int d0 = blockIdx.y * kc;
  float acc[BB];
#pragma unroll
  for (int b = 0; b < BB; ++b) acc[b] = 0.0f;
  const float* wp = W + (size_t)d0 * VV + vc;
  const float* xr = xT + d0 * BB;
#pragma unroll 2
  for (int d = 0; d < kc; ++d) {
    const float w = wp[(size_t)d * VV];
    const float* xv = xr + d * BB;   // wave-uniform -> scalar loads
#pragma unroll
    for (int b = 0; b < BB; ++b) acc[b] = fmaf(xv[b], w, acc[b]);
  }
  if (v < VV) {
    float* pp = partial + (size_t)blockIdx.y * BB * VV + v;
#pragma unroll
    for (int b = 0; b < BB; ++b) pp[(size_t)b * VV] = acc[b];
  }
}

__global__ __launch_bounds__(256) void reduce_bias_kernel(
    const float* __restrict__ partial, const float* __restrict__ bias,
    float* __restrict__ logits, int sk) {
  size_t i = (size_t)blockIdx.x * 256 + threadIdx.x;
  if (i >= (size_t)BB * VV) return;
  int b = (int)(i / VV);
  int v = (int)(i - (size_t)b * VV);
  float acc = bias[v];
  for (int s = 0; s < sk; ++s)
    acc += partial[((size_t)s * BB + b) * VV + v];
  logits[i] = acc;
}

// Legacy fused GEMM (validated R5) — fallback if ws too small for split-K.
__global__ __launch_bounds__(256, 1) void gemm_kernel(
    const float* __restrict__ xT, const float* __restrict__ W,
    const float* __restrict__ bias, float* __restrict__ logits) {
  const int v = blockIdx.x * 256 + threadIdx.x;
  const int vc = (v < VV) ? v : (VV - 1);
  float acc[BB];
#pragma unroll
  for (int b = 0; b < BB; ++b) acc[b] = 0.0f;
  const float* wp = W + vc;
#pragma unroll 2
  for (int d = 0; d < DD; ++d) {
    const float w = wp[(size_t)d * VV];
    const float* xr = xT + d * BB;
#pragma unroll
    for (int b = 0; b < BB; ++b) acc[b] = fmaf(xr[b], w, acc[b]);
  }
  if (v < VV) {
    const float bv = bias[v];
#pragma unroll
    for (int b = 0; b < BB; ++b) logits[(size_t)b * VV + v] = acc[b] + bv;
  }
}

// Per row: max -> histogram of w=expf(z-m) binned by (m-z)*256 -> scan to find
// boundary bin (S_above <= C < S_above+bin) -> exact prefix sums within bin
// ((key desc, idx asc) order, same semantics as R5's validated binary search)
// -> t* = min kept key -> gumbel argmax over key >= t*. 4 logits passes vs 35.
__global__ __launch_bounds__(1024) void nucleus_sample_kernel(
    const float* __restrict__ logits, int* __restrict__ out) {
  __shared__ double sd[1024];
  __shared__ float sf[1024];
  __shared__ unsigned su[1024];
  __shared__ int si[1024];
  __shared__ double bins[NB];
  __shared__ int cidx[MAXC];
  __shared__ unsigned ckey[MAXC];
  __shared__ double cw[MAXC];
  __shared__ int ccount;
  __shared__ int sh_chunk;
  __shared__ int sh_bstar;
  __shared__ double sh_sabove;

  const int row = blockIdx.x;
  const int tid = threadIdx.x;
  const float* z = logits + (size_t)row * VV;

  for (int i = tid; i < NB; i += 1024) bins[i] = 0.0;
  if (tid == 0) { ccount = 0; sh_chunk = -1; sh_bstar = -1; }
  __syncthreads();

  // pass 1: row max
  float mx = -3.4e38f;
  for (int i = tid; i < VV; i += 1024) mx = fmaxf(mx, z[i]);
  sf[tid] = mx; __syncthreads();
  for (int s = 512; s > 0; s >>= 1) {
    if (tid < s) sf[tid] = fmaxf(sf[tid], sf[tid + s]);
    __syncthreads();
  }
  const float m = sf[0];
  __syncthreads();

  // pass 2: histogram
  for (int i = tid; i < VV; i += 1024) {
    float zi = z[i];
    int bin = (int)((m - zi) * 256.0f);
    bin = (bin < 0) ? 0 : ((bin > NB - 1) ? NB - 1 : bin);
    atomicAdd(&bins[bin], (double)expf(zi - m));
  }
  __syncthreads();

  // inclusive scan over 1024 chunk-sums (4 bins/chunk), f64
  {
    double c = bins[4 * tid] + bins[4 * tid + 1] + bins[4 * tid + 2] + bins[4 * tid + 3];
    sd[tid] = c; __syncthreads();
    for (int off = 1; off < 1024; off <<= 1) {
      double vv = (tid >= off) ? sd[tid - off] : 0.0;
      __syncthreads();
      sd[tid] += vv;
      __syncthreads();
    }
  }
  const double Z = sd[1023];
  const double C = (double)0.9f * Z;

  if (sd[tid] > C && (tid == 0 || sd[tid - 1] <= C)) sh_chunk = tid;
  __syncthreads();
  if (tid == 0) {
    int tc = sh_chunk;
    if (tc >= 0) {
      double run = (tc > 0) ? sd[tc - 1] : 0.0;
      for (int k = 0; k < 4; ++k) {
        double bw = bins[4 * tc + k];
        if (run + bw > C) { sh_bstar = 4 * tc + k; sh_sabove = run; break; }
        run += bw;
      }
    }
  }
  __syncthreads();
  const int bstar = sh_bstar;
  unsigned tkey = 0u;

  if (bstar >= 0) {
    const double Sab = sh_sabove;
    // pass 3: collect boundary-bin elements
    for (int i = tid; i < VV; i += 1024) {
      float zi = z[i];
      int bin = (int)((m - zi) * 256.0f);
      bin = (bin < 0) ? 0 : ((bin > NB - 1) ? NB - 1 : bin);
      if (bin == bstar) {
        int slot = atomicAdd(&ccount, 1);
        if (slot < MAXC) {
          ckey[slot] = mono_key(zi);
          cidx[slot] = i;
          cw[slot] = (double)expf(zi - m);
        }
      }
    }
    __syncthreads();
    int n = ccount; if (n > MAXC) n = MAXC;
    // kept iff exclusive prefix (in (key desc, idx asc) order) <= C
    unsigned mk = 0xFFFFFFFFu;
    for (int i = tid; i < n; i += 1024) {
      unsigned ki = ckey[i]; int ii = cidx[i];
      double T = Sab;
      for (int j = 0; j < n; ++j) {
        unsigned kj = ckey[j];
        if (kj > ki || (kj == ki && cidx[j] < ii)) T += cw[j];
      }
      if (T <= C) mk = (ki < mk) ? ki : mk;
    }
    su[tid] = mk; __syncthreads();
    for (int s = 512; s > 0; s >>= 1) {
      if (tid < s) su[tid] = min(su[tid], su[tid + s]);
      __syncthreads();
    }
    tkey = su[0];
    __syncthreads();
  }
  const unsigned tstar = tkey;

  // pass 4: gumbel argmax over kept tokens (validated R5 code path)
  float best = -3.4e38f; int bidx = 0x7FFFFFFF;
  for (int i = tid; i < VV; i += 1024) {
    float zi = z[i];
    if (mono_key(zi) < tstar) continue;
    unsigned e = (unsigned)row * (unsigned)VV + (unsigned)i;
    unsigned bits = jax_random_bits(e);
    float f = __uint_as_float((bits >> 9) | 0x3F800000u) - 1.0f;
    float u = fmaxf(1.17549435082228750797e-38f, f);
    float g = -logf(-logf(u));
    float sc = zi + g;
    if (sc > best) { best = sc; bidx = i; }
  }
  sf[tid] = best; si[tid] = bidx; __syncthreads();
  for (int s = 512; s > 0; s >>= 1) {
    if (tid < s) {
      float ob = sf[tid + s]; int oi = si[tid + s];
      if (ob > sf[tid] || (ob == sf[tid] && oi < si[tid])) {
        sf[tid] = ob; si[tid] = oi;
      }
    }
    __syncthreads();
  }
  if (tid == 0) out[row] = si[0];
}

extern "C" void kernel_launch(void* const* d_in, const int* in_sizes, int n_in,
                              void* d_out, int out_size, void* d_ws, size_t ws_size,
                              hipStream_t stream) {
  const float* x = (const float*)d_in[0];
  const float* W = (const float*)d_in[1];
  const float* bias = (const float*)d_in[2];
  int* out = (int*)d_out;
  char* ws = (char*)d_ws;

  const size_t offXT = 0;                       // 524288 B
  const size_t offLog = 524288;                 // 12865792 B
  const size_t offPart = offLog + 12865792;     // sk * 12865792 B
  float* xT = (float*)(ws + offXT);
  float* logits = (float*)(ws + offLog);
  float* partial = (float*)(ws + offPart);

  int sk = 0;
  for (int c = 8; c >= 2; c >>= 1) {
    if (offPart + (size_t)c * 12865792 <= ws_size) { sk = c; break; }
  }

  transpose_kernel<<<(BB * DD + 255) / 256, 256, 0, stream>>>(x, xT);
  const int vblocks = (VV + 255) / 256;
  if (sk) {
    dim3 g(vblocks, sk);
    gemm_splitk_kernel<<<g, 256, 0, stream>>>(xT, W, partial, DD / sk);
    const size_t tot = (size_t)BB * VV;
    reduce_bias_kernel<<<(unsigned)((tot + 255) / 256), 256, 0, stream>>>(
        partial, bias, logits, sk);
  } else {
    gemm_kernel<<<vblocks, 256, 0, stream>>>(xT, W, bias, logits);
  }
  nucleus_sample_kernel<<<BB, 1024, 0, stream>>>(logits, out);
}